// Round 6
// baseline (346.934 us; speedup 1.0000x reference)
//
#include <hip/hip_runtime.h>
#include <hip/hip_bf16.h>

#define N_NODES 50000
#define N_EDGES 800000
#define N_GRAPH 128
#define NC      10

// bucket sort params
#define NBKT  391        // ceil(50000/128) buckets of 128 node ids
#define BLK_E 4096       // edges per pass-A block
#define NPT   16         // edges per thread in pass A (BLK_E/256)
#define BCAP  2560       // capacity per bucket region (avg 2046, 11 sigma slack)

typedef __attribute__((ext_vector_type(8))) short bf16x8;
typedef __attribute__((ext_vector_type(4))) float f32x4;

static constexpr size_t alignup(size_t x) { return (x + 511) & ~size_t(511); }

// ---------------- workspace layout (bytes) ----------------
static constexpr size_t OFS_IM    = 0;                                           // [N,128] f32 input_message
static constexpr size_t OFS_CURB0 = alignup(OFS_IM  + (size_t)N_NODES*128*4);    // [N,128] bf16 ping
static constexpr size_t OFS_CURB1 = alignup(OFS_CURB0 + (size_t)N_NODES*128*2);  // [N,128] bf16 pong
static constexpr size_t OFS_OFF   = alignup(OFS_CURB1 + (size_t)N_NODES*128*2);  // [N+1] int
static constexpr size_t OFS_GCUR  = alignup(OFS_OFF + (size_t)(N_NODES+1)*4);    // [512] int bucket cursors
static constexpr size_t OFS_CSB   = alignup(OFS_GCUR + 2048);                    // [512] int bucket csr base
static constexpr size_t OFS_CSR   = alignup(OFS_CSB + 2048);                     // [E] int
static constexpr size_t OFS_BKT   = alignup(OFS_CSR + (size_t)N_EDGES*4);        // [NBKT*BCAP] u32
static constexpr size_t OFS_EMB   = alignup(OFS_BKT + (size_t)NBKT*BCAP*4);      // [128,128] f32
static constexpr size_t OFS_NLL   = alignup(OFS_EMB + 128*128*4);                // [128] f32
static constexpr size_t OFS_COR   = alignup(OFS_NLL + 128*4);                    // [128] f32
static constexpr size_t OFS_WPK   = alignup(OFS_COR + 128*4);                    // 3 mats x 2 halves x 16384 ushort

__device__ __forceinline__ unsigned short f2bf(float f)
{
    unsigned u = __float_as_uint(f);
    u += 0x7fffu + ((u >> 16) & 1u);          // RNE
    return (unsigned short)(u >> 16);
}

// =====================================================================
// Setup: pack 3 weight matrices into MFMA fragment order (bf16 hi+lo)
// AND zero gcur/embed — one launch, no rocclr fill blits in the graph.
// Blocks 0..191: pack (64 blocks per matrix). Blocks 192..255: zeroing.
// frag index: f = ((ct*4 + ks)*64 + lane)*8 + j
//   c = ct*16 + (lane&15), k = ks*32 + (lane>>4)*8 + j
// =====================================================================
__global__ __launch_bounds__(256) void setup_kernel(
    const float* __restrict__ W0, const float* __restrict__ W1, const float* __restrict__ W2,
    unsigned short* __restrict__ wpk,   // [6][16384]: w0h w0l w1h w1l w2h w2l
    int* __restrict__ gcur, float* __restrict__ embed)
{
    int b = blockIdx.x;
    if (b < 192) {
        int mat = b >> 6;
        const float* W = (mat == 0) ? W0 : (mat == 1) ? W1 : W2;
        unsigned short* Wh = wpk + (size_t)(2 * mat) * 16384;
        unsigned short* Wl = Wh + 16384;
        int f = (b & 63) * 256 + threadIdx.x;
        int j    = f & 7;
        int lane = (f >> 3) & 63;
        int ctks = f >> 9;
        int ct = ctks >> 2, ks = ctks & 3;
        int c = ct * 16 + (lane & 15);
        int k = ks * 32 + (lane >> 4) * 8 + j;
        float v = W[c * 128 + k];
        unsigned short h = f2bf(v);
        float hf = __uint_as_float((unsigned)h << 16);
        Wh[f] = h;
        Wl[f] = f2bf(v - hf);
    } else {
        int i = (b - 192) * 256 + threadIdx.x;   // 0..16383
        embed[i] = 0.f;
        if (i < 512) gcur[i] = 0;
    }
}

// =====================================================================
// MFMA GEMM (C^T tiles, no LDS): mfma(A_op = W-tile, B_op = node rows).
// 16 nodes/wave, 4 waves/block. hi/lo bf16 split keeps f32-level accuracy.
// =====================================================================
template <bool A_F32>
__global__ __launch_bounds__(256) void gemm_mfma(
    const void* __restrict__ Aptr,
    const unsigned short* __restrict__ Wh, const unsigned short* __restrict__ Wl,
    const float* __restrict__ bias,
    unsigned short* __restrict__ out_relu_bf16,
    float* __restrict__ out_raw_f32, int M)
{
    int wid  = threadIdx.x >> 6;
    int lane = threadIdx.x & 63;
    int n0 = blockIdx.x * 64 + wid * 16;
    if (n0 >= M) return;
    int kb = lane >> 4;
    int row = n0 + (lane & 15);

    f32x4 acc[8];
#pragma unroll
    for (int ct = 0; ct < 8; ++ct) acc[ct] = (f32x4){0.f, 0.f, 0.f, 0.f};

#pragma unroll
    for (int ks = 0; ks < 4; ++ks) {
        bf16x8 ah, al;
        if (A_F32) {
            const float* A = (const float*)Aptr;
            f32x4 a0 = *(const f32x4*)(A + (size_t)row * 128 + ks * 32 + kb * 8);
            f32x4 a1 = *(const f32x4*)(A + (size_t)row * 128 + ks * 32 + kb * 8 + 4);
            float av[8] = {a0[0], a0[1], a0[2], a0[3], a1[0], a1[1], a1[2], a1[3]};
#pragma unroll
            for (int j = 0; j < 8; ++j) {
                unsigned short h = f2bf(av[j]);
                float hf = __uint_as_float((unsigned)h << 16);
                ah[j] = (short)h;
                al[j] = (short)f2bf(av[j] - hf);
            }
        } else {
            ah = *(const bf16x8*)((const unsigned short*)Aptr + (size_t)row * 128 + ks * 32 + kb * 8);
        }
#pragma unroll
        for (int ct = 0; ct < 8; ++ct) {
            size_t wf = ((size_t)(ct * 4 + ks) * 64 + lane) * 8;
            bf16x8 wh = *(const bf16x8*)(Wh + wf);
            bf16x8 wl = *(const bf16x8*)(Wl + wf);
            acc[ct] = __builtin_amdgcn_mfma_f32_16x16x32_bf16(wh, ah, acc[ct], 0, 0, 0);
            if (A_F32)
                acc[ct] = __builtin_amdgcn_mfma_f32_16x16x32_bf16(wh, al, acc[ct], 0, 0, 0);
            acc[ct] = __builtin_amdgcn_mfma_f32_16x16x32_bf16(wl, ah, acc[ct], 0, 0, 0);
        }
    }

#pragma unroll
    for (int ct = 0; ct < 8; ++ct) {
        int c0 = ct * 16 + kb * 4;
        f32x4 r = acc[ct];
        f32x4 bv = *(const f32x4*)(bias + c0);
        r += bv;
        if (out_raw_f32) *(f32x4*)(out_raw_f32 + (size_t)row * 128 + c0) = r;
        r[0] = fmaxf(r[0], 0.f); r[1] = fmaxf(r[1], 0.f);
        r[2] = fmaxf(r[2], 0.f); r[3] = fmaxf(r[3], 0.f);
        if (out_relu_bf16) {
            ushort4 ob;
            ob.x = f2bf(r[0]); ob.y = f2bf(r[1]); ob.z = f2bf(r[2]); ob.w = f2bf(r[3]);
            *(ushort4*)(out_relu_bf16 + (size_t)row * 128 + c0) = ob;
        }
    }
}

// =====================================================================
// FUSED level kernel: agg = spmm(csr, Xin); cur_out = relu(agg@Wc.T + b + im)
// Block = 256 threads / 4 waves / 64 nodes.
// Phase 1: wave-per-node coalesced gather+sum into LDS sAgg[64][132].
// Phase 2: per-wave MFMA from LDS fragments (f32x4 reads, 16B aligned,
//          exactly 8 lanes/bank = structural minimum, conflict-free).
// =====================================================================
__global__ __launch_bounds__(256) void spmm_gemm_fused(
    const int* __restrict__ off, const int* __restrict__ csr,
    const unsigned short* __restrict__ Xin,
    const unsigned short* __restrict__ Wh, const unsigned short* __restrict__ Wl,
    const float* __restrict__ bias, const float* __restrict__ im,
    unsigned short* __restrict__ out_bf16, int M)
{
    __shared__ float sAgg[64][132];     // 33792 B, padded
    int t = threadIdx.x;
    int w = t >> 6, lane = t & 63;
    int n0 = blockIdx.x * 64;

    // ---- phase 1: gather + sum (wave w handles rows w, w+4, ...) ----
    for (int i = 0; i < 16; ++i) {
        int r = (i << 2) | w;
        int n = n0 + r;
        float ax = 0.f, ay = 0.f;
        if (n < M) {
            int lo = off[n], hi = off[n + 1];
            int e = lo;
            for (; e + 4 <= hi; e += 4) {
                int s0 = csr[e], s1 = csr[e + 1], s2 = csr[e + 2], s3 = csr[e + 3];
                unsigned v0 = *(const unsigned*)(Xin + (size_t)s0 * 128 + 2 * lane);
                unsigned v1 = *(const unsigned*)(Xin + (size_t)s1 * 128 + 2 * lane);
                unsigned v2 = *(const unsigned*)(Xin + (size_t)s2 * 128 + 2 * lane);
                unsigned v3 = *(const unsigned*)(Xin + (size_t)s3 * 128 + 2 * lane);
                ax += __uint_as_float(v0 << 16) + __uint_as_float(v1 << 16)
                    + __uint_as_float(v2 << 16) + __uint_as_float(v3 << 16);
                ay += __uint_as_float(v0 & 0xffff0000u) + __uint_as_float(v1 & 0xffff0000u)
                    + __uint_as_float(v2 & 0xffff0000u) + __uint_as_float(v3 & 0xffff0000u);
            }
            for (; e < hi; ++e) {
                unsigned v = *(const unsigned*)(Xin + (size_t)csr[e] * 128 + 2 * lane);
                ax += __uint_as_float(v << 16);
                ay += __uint_as_float(v & 0xffff0000u);
            }
        }
        float2 st; st.x = ax; st.y = ay;
        *(float2*)&sAgg[r][2 * lane] = st;
    }
    __syncthreads();

    // ---- phase 2: MFMA (wave w owns rows w*16 .. w*16+15) ----
    int kb = lane >> 4;
    int r  = (w << 4) | (lane & 15);
    int row = n0 + r;

    f32x4 acc[8];
#pragma unroll
    for (int ct = 0; ct < 8; ++ct) acc[ct] = (f32x4){0.f, 0.f, 0.f, 0.f};

#pragma unroll
    for (int ks = 0; ks < 4; ++ks) {
        f32x4 a0 = *(const f32x4*)&sAgg[r][ks * 32 + kb * 8];
        f32x4 a1 = *(const f32x4*)&sAgg[r][ks * 32 + kb * 8 + 4];
        float av[8] = {a0[0], a0[1], a0[2], a0[3], a1[0], a1[1], a1[2], a1[3]};
        bf16x8 ah, al;
#pragma unroll
        for (int j = 0; j < 8; ++j) {
            unsigned short h = f2bf(av[j]);
            float hf = __uint_as_float((unsigned)h << 16);
            ah[j] = (short)h;
            al[j] = (short)f2bf(av[j] - hf);
        }
#pragma unroll
        for (int ct = 0; ct < 8; ++ct) {
            size_t wf = ((size_t)(ct * 4 + ks) * 64 + lane) * 8;
            bf16x8 wh = *(const bf16x8*)(Wh + wf);
            bf16x8 wl = *(const bf16x8*)(Wl + wf);
            acc[ct] = __builtin_amdgcn_mfma_f32_16x16x32_bf16(wh, ah, acc[ct], 0, 0, 0);
            acc[ct] = __builtin_amdgcn_mfma_f32_16x16x32_bf16(wh, al, acc[ct], 0, 0, 0);
            acc[ct] = __builtin_amdgcn_mfma_f32_16x16x32_bf16(wl, ah, acc[ct], 0, 0, 0);
        }
    }

    if (row < M) {
#pragma unroll
        for (int ct = 0; ct < 8; ++ct) {
            int c0 = ct * 16 + kb * 4;
            f32x4 rr = acc[ct];
            f32x4 bv = *(const f32x4*)(bias + c0);
            f32x4 mv = *(const f32x4*)(im + (size_t)row * 128 + c0);
            rr += bv; rr += mv;
            rr[0] = fmaxf(rr[0], 0.f); rr[1] = fmaxf(rr[1], 0.f);
            rr[2] = fmaxf(rr[2], 0.f); rr[3] = fmaxf(rr[3], 0.f);
            ushort4 ob;
            ob.x = f2bf(rr[0]); ob.y = f2bf(rr[1]); ob.z = f2bf(rr[2]); ob.w = f2bf(rr[3]);
            *(ushort4*)(out_bf16 + (size_t)row * 128 + c0) = ob;
        }
    }
}

// =====================================================================
// Pass A: LDS counting-sort 4096 edges into 391 coarse buckets (dst>>7),
// write each bucket run contiguously to its global region (atomic reserve).
// Edge packed as (src<<7)|(dst&127) — 4B.
// =====================================================================
__global__ __launch_bounds__(256) void bucket_a(
    const int* __restrict__ esrc, const int* __restrict__ edst,
    int* __restrict__ gcur, unsigned* __restrict__ bdata)
{
    __shared__ unsigned sp[BLK_E];      // 16KB
    __shared__ int shist[512];
    __shared__ int sscan[512];
    __shared__ int sgbase[NBKT];
    __shared__ int scur[NBKT];
    __shared__ int wtot[4];

    int t = threadIdx.x;
    int e0 = blockIdx.x * BLK_E;
    shist[t] = 0; shist[t + 256] = 0;
    __syncthreads();

    int vv[NPT]; int bb[NPT];
#pragma unroll
    for (int i = 0; i < NPT; ++i) {
        int e = e0 + t + i * 256;
        if (e < N_EDGES) {
            int s = esrc[e], d = edst[e];
            bb[i] = d >> 7;
            vv[i] = (s << 7) | (d & 127);
            atomicAdd(&shist[bb[i]], 1);
        } else bb[i] = -1;
    }
    __syncthreads();

    // exclusive scan of 512 counts
    {
        int lane = t & 63, w = t >> 6;
        int a0 = shist[2 * t], a1 = shist[2 * t + 1];
        int s = a0 + a1, inc = s;
#pragma unroll
        for (int d = 1; d < 64; d <<= 1) {
            int y = __shfl_up(inc, d, 64);
            if (lane >= d) inc += y;
        }
        if (lane == 63) wtot[w] = inc;
        __syncthreads();
        int woff = 0;
        for (int j = 0; j < w; ++j) woff += wtot[j];
        int excl = woff + inc - s;
        sscan[2 * t] = excl;
        sscan[2 * t + 1] = excl + a0;
    }
    __syncthreads();

    // reserve global space per bucket; init local cursors
    for (int b = t; b < NBKT; b += 256) {
        int c = shist[b];
        sgbase[b] = c ? atomicAdd(&gcur[b], c) : 0;
        scur[b] = sscan[b];
    }
    __syncthreads();

    // scatter into LDS grouped by bucket
#pragma unroll
    for (int i = 0; i < NPT; ++i) {
        if (bb[i] >= 0) {
            int pos = atomicAdd(&scur[bb[i]], 1);
            sp[pos] = (unsigned)vv[i];
        }
    }
    __syncthreads();

    // copy runs out: wave w handles buckets w, w+4, ...
    int lane = t & 63, w = t >> 6;
    for (int b = w; b < NBKT; b += 4) {
        int c = shist[b];
        int lo = sscan[b];
        unsigned gb = (unsigned)b * BCAP + (unsigned)sgbase[b];
        for (int j = lane; j < c; j += 64)
            bdata[gb + j] = sp[lo + j];
    }
}

// =====================================================================
// Exclusive scan of 391 bucket counts -> csr base per bucket; off[N]=E.
// =====================================================================
__global__ __launch_bounds__(256) void scan_buckets(
    const int* __restrict__ gcur, int* __restrict__ csrbase, int* __restrict__ off)
{
    __shared__ int wtot[4];
    int t = threadIdx.x;
    int lane = t & 63, w = t >> 6;
    int a0 = (2 * t < NBKT) ? gcur[2 * t] : 0;
    int a1 = (2 * t + 1 < NBKT) ? gcur[2 * t + 1] : 0;
    int s = a0 + a1, inc = s;
#pragma unroll
    for (int d = 1; d < 64; d <<= 1) {
        int y = __shfl_up(inc, d, 64);
        if (lane >= d) inc += y;
    }
    if (lane == 63) wtot[w] = inc;
    __syncthreads();
    int woff = 0;
    for (int j = 0; j < w; ++j) woff += wtot[j];
    int excl = woff + inc - s;
    if (2 * t < NBKT) csrbase[2 * t] = excl;
    if (2 * t + 1 < NBKT) csrbase[2 * t + 1] = excl + a0;
    if (t == 0) off[N_NODES] = N_EDGES;
}

// =====================================================================
// Pass B: per bucket, LDS counting-sort by dst&127; write off[] and csr
// fully sequentially.
// =====================================================================
__global__ __launch_bounds__(256) void bucket_b(
    const int* __restrict__ gcur, const int* __restrict__ csrbase,
    const unsigned* __restrict__ bdata,
    int* __restrict__ off, int* __restrict__ csr)
{
    __shared__ unsigned sp[BCAP];       // 10KB
    __shared__ unsigned sq[BCAP];       // 10KB
    __shared__ int h[128], sc[128], cur[128];

    int b = blockIdx.x;
    int t = threadIdx.x;
    int cnt = gcur[b];
    if (cnt > BCAP) cnt = BCAP;         // defensive (statistically impossible)
    const unsigned* reg = bdata + (size_t)b * BCAP;

    if (t < 128) h[t] = 0;
    __syncthreads();
    for (int i = t; i < cnt; i += 256) {
        unsigned v = reg[i];
        sp[i] = v;
        atomicAdd(&h[v & 127], 1);
    }
    __syncthreads();
    if (t < 64) {
        int a0 = h[2 * t], a1 = h[2 * t + 1];
        int s = a0 + a1, inc = s;
#pragma unroll
        for (int d = 1; d < 64; d <<= 1) {
            int y = __shfl_up(inc, d, 64);
            if (t >= d) inc += y;
        }
        int excl = inc - s;
        sc[2 * t] = excl;          cur[2 * t] = excl;
        sc[2 * t + 1] = excl + a0; cur[2 * t + 1] = excl + a0;
    }
    __syncthreads();
    int base = csrbase[b];
    if (t < 128) {
        int node = b * 128 + t;
        if (node < N_NODES) off[node] = base + sc[t];
    }
    for (int i = t; i < cnt; i += 256) {
        unsigned v = sp[i];
        int pos = atomicAdd(&cur[v & 127], 1);
        sq[pos] = v >> 7;
    }
    __syncthreads();
    for (int i = t; i < cnt; i += 256)
        csr[base + i] = (int)sq[i];
}

// =====================================================================
// Per-graph sum pooling (bf16 input): chunked partial sums + atomicAdd.
// =====================================================================
#define PCHUNK 64
__global__ __launch_bounds__(128) void pool_partial(
    const unsigned short* __restrict__ X, const int* __restrict__ gid,
    float* __restrict__ embed)
{
    int n0 = blockIdx.x * PCHUNK;
    int t = threadIdx.x;
    int end = n0 + PCHUNK; if (end > N_NODES) end = N_NODES;
    float acc = 0.f;
    int g = gid[n0];
    for (int n = n0; n < end; ++n) {
        int gn = gid[n];
        if (gn != g) {
            atomicAdd(&embed[g * 128 + t], acc);
            acc = 0.f; g = gn;
        }
        acc += __uint_as_float((unsigned)X[(size_t)n * 128 + t] << 16);
    }
    atomicAdd(&embed[g * 128 + t], acc);
}

// =====================================================================
// Classifier head (f32).
// =====================================================================
__global__ __launch_bounds__(256) void head_kernel(
    const float* __restrict__ embed,
    const float* __restrict__ w_h1, const float* __restrict__ b_h1,
    const float* __restrict__ w_h2, const float* __restrict__ b_h2,
    const int* __restrict__ labels,
    float* __restrict__ logits, float* __restrict__ nll, float* __restrict__ corr)
{
    int g = blockIdx.x;
    int t = threadIdx.x;
    __shared__ float se[128];
    __shared__ float sh[256];
    __shared__ float sl[NC];
    __shared__ float s_lse;
    if (t < 128) se[t] = fmaxf(embed[g * 128 + t], 0.f);
    __syncthreads();

    float h = b_h1[t];
    const float* wr = w_h1 + (size_t)t * 128;
    for (int k = 0; k < 128; ++k) h += se[k] * wr[k];
    sh[t] = fmaxf(h, 0.f);
    __syncthreads();

    if (t < NC) {
        float z = b_h2[t];
        const float* w2 = w_h2 + (size_t)t * 256;
        for (int k = 0; k < 256; ++k) z += sh[k] * w2[k];
        sl[t] = z;
    }
    __syncthreads();

    if (t == 0) {
        float m = sl[0];
        int am = 0;
        for (int c = 1; c < NC; ++c) if (sl[c] > m) { m = sl[c]; am = c; }
        float s = 0.f;
        for (int c = 0; c < NC; ++c) s += expf(sl[c] - m);
        float lse = m + logf(s);
        s_lse = lse;
        int lab = labels[g];
        nll[g] = lse - sl[lab];
        corr[g] = (am == lab) ? 1.f : 0.f;
    }
    __syncthreads();
    if (t < NC) logits[g * NC + t] = sl[t] - s_lse;
}

__global__ __launch_bounds__(64) void finalize_kernel(
    const float* __restrict__ nll, const float* __restrict__ corr,
    float* __restrict__ out)
{
    int t = threadIdx.x;
    float a = nll[t] + nll[t + 64];
    float b = corr[t] + corr[t + 64];
    for (int d = 32; d; d >>= 1) {
        a += __shfl_down(a, d);
        b += __shfl_down(b, d);
    }
    if (t == 0) {
        out[N_GRAPH * NC + 0] = a / (float)N_GRAPH;
        out[N_GRAPH * NC + 1] = b / (float)N_GRAPH;
    }
}

// =====================================================================
extern "C" void kernel_launch(void* const* d_in, const int* in_sizes, int n_in,
                              void* d_out, int out_size, void* d_ws, size_t ws_size,
                              hipStream_t stream)
{
    const float* node_feat = (const float*)d_in[0];
    const int*   edge_src  = (const int*)d_in[1];
    const int*   edge_dst  = (const int*)d_in[2];
    const int*   graph_id  = (const int*)d_in[3];
    const int*   labels    = (const int*)d_in[4];
    const float* w_n2l     = (const float*)d_in[5];
    const float* b_n2l     = (const float*)d_in[6];
    const float* w_conv    = (const float*)d_in[7];
    const float* b_conv    = (const float*)d_in[8];
    const float* w_out     = (const float*)d_in[9];
    const float* b_out     = (const float*)d_in[10];
    const float* w_h1      = (const float*)d_in[11];
    const float* b_h1      = (const float*)d_in[12];
    const float* w_h2      = (const float*)d_in[13];
    const float* b_h2      = (const float*)d_in[14];

    char* ws = (char*)d_ws;
    float*          im      = (float*)(ws + OFS_IM);
    unsigned short* curb0   = (unsigned short*)(ws + OFS_CURB0);
    unsigned short* curb1   = (unsigned short*)(ws + OFS_CURB1);
    int*            off     = (int*)(ws + OFS_OFF);
    int*            gcur    = (int*)(ws + OFS_GCUR);
    int*            csrbase = (int*)(ws + OFS_CSB);
    int*            csr     = (int*)(ws + OFS_CSR);
    unsigned*       bdata   = (unsigned*)(ws + OFS_BKT);
    float*          embed   = (float*)(ws + OFS_EMB);
    float*          nll     = (float*)(ws + OFS_NLL);
    float*          corr    = (float*)(ws + OFS_COR);
    unsigned short* wpk     = (unsigned short*)(ws + OFS_WPK);
    unsigned short* w0h = wpk;              unsigned short* w0l = wpk + 16384;
    unsigned short* w1h = wpk + 2 * 16384;  unsigned short* w1l = wpk + 3 * 16384;
    unsigned short* w2h = wpk + 4 * 16384;  unsigned short* w2l = wpk + 5 * 16384;
    float*          outp    = (float*)d_out;

    const int gemm_blocks = (N_NODES + 63) / 64;
    const int pool_blocks = (N_NODES + PCHUNK - 1) / PCHUNK;
    const int bktA_blocks = (N_EDGES + BLK_E - 1) / BLK_E;

    // 0. pack weights (MFMA fragment order, hi/lo) + zero gcur/embed
    setup_kernel<<<256, 256, 0, stream>>>(w_n2l, w_conv, w_out, wpk, gcur, embed);

    // 1. input_message (raw -> im) ; curb0 = bf16(relu(im))
    gemm_mfma<true><<<gemm_blocks, 256, 0, stream>>>(
        node_feat, w0h, w0l, b_n2l, curb0, im, N_NODES);

    // 2. build CSR by dst (two-pass bucket sort, cache-friendly writes)
    bucket_a<<<bktA_blocks, 256, 0, stream>>>(edge_src, edge_dst, gcur, bdata);
    scan_buckets<<<1, 256, 0, stream>>>(gcur, csrbase, off);
    bucket_b<<<NBKT, 256, 0, stream>>>(gcur, csrbase, bdata, off, csr);

    // 3. three fused mean-field levels (ping-pong cur buffers)
    unsigned short* cA = curb0;
    unsigned short* cB = curb1;
    for (int lv = 0; lv < 3; ++lv) {
        spmm_gemm_fused<<<gemm_blocks, 256, 0, stream>>>(
            off, csr, cA, w1h, w1l, b_conv, im, cB, N_NODES);
        unsigned short* tmp = cA; cA = cB; cB = tmp;
    }
    // final cur is in cA (= curb1 after 3 levels)

    // 4. out = relu(cA @ w_out.T + b_out) -> bf16 into cB (free buffer)
    gemm_mfma<false><<<gemm_blocks, 256, 0, stream>>>(
        cA, w2h, w2l, b_out, cB, nullptr, N_NODES);

    // 5. per-graph pooling (sum, relu deferred to head)
    pool_partial<<<pool_blocks, 128, 0, stream>>>(cB, graph_id, embed);

    // 6. classifier head
    head_kernel<<<N_GRAPH, 256, 0, stream>>>(embed, w_h1, b_h1, w_h2, b_h2, labels,
                                             outp, nll, corr);

    // 7. loss & acc
    finalize_kernel<<<1, 64, 0, stream>>>(nll, corr, outp);
}

// Round 7
// 264.336 us; speedup vs baseline: 1.3125x; 1.3125x over previous
//
#include <hip/hip_runtime.h>
#include <hip/hip_bf16.h>

#define N_NODES 50000
#define N_EDGES 800000
#define N_GRAPH 128
#define NC      10

// bucket sort params
#define NBKT  391        // ceil(50000/128) buckets of 128 node ids
#define BLK_E 4096       // edges per pass-A block
#define NPT   16         // edges per thread in pass A (BLK_E/256)
#define BCAP  2560       // capacity per bucket region (avg 2046, 11 sigma slack)

typedef __attribute__((ext_vector_type(8))) short bf16x8;
typedef __attribute__((ext_vector_type(4))) float f32x4;

static constexpr size_t alignup(size_t x) { return (x + 511) & ~size_t(511); }

// ---------------- workspace layout (bytes) ----------------
static constexpr size_t OFS_IM    = 0;                                           // [N,128] f32 input_message
static constexpr size_t OFS_CURB  = alignup(OFS_IM  + (size_t)N_NODES*128*4);    // [N,128] bf16 cur
static constexpr size_t OFS_ZB    = alignup(OFS_CURB + (size_t)N_NODES*128*2);   // [N,128] bf16 z / out
static constexpr size_t OFS_OFF   = alignup(OFS_ZB + (size_t)N_NODES*128*2);     // [N+1] int
static constexpr size_t OFS_GCUR  = alignup(OFS_OFF + (size_t)(N_NODES+1)*4);    // [512] int bucket cursors
static constexpr size_t OFS_CSB   = alignup(OFS_GCUR + 2048);                    // [512] int bucket csr base
static constexpr size_t OFS_CSR   = alignup(OFS_CSB + 2048);                     // [E] int
static constexpr size_t OFS_BKT   = alignup(OFS_CSR + (size_t)N_EDGES*4);        // [NBKT*BCAP] u32
static constexpr size_t OFS_EMB   = alignup(OFS_BKT + (size_t)NBKT*BCAP*4);      // [128,128] f32
static constexpr size_t OFS_NLL   = alignup(OFS_EMB + 128*128*4);                // [128] f32
static constexpr size_t OFS_COR   = alignup(OFS_NLL + 128*4);                    // [128] f32
static constexpr size_t OFS_WPK   = alignup(OFS_COR + 128*4);                    // 3 mats x 2 halves x 16384 ushort

__device__ __forceinline__ unsigned short f2bf(float f)
{
    unsigned u = __float_as_uint(f);
    u += 0x7fffu + ((u >> 16) & 1u);          // RNE
    return (unsigned short)(u >> 16);
}

// =====================================================================
// Setup: pack 3 weight matrices into MFMA fragment order (bf16 hi+lo)
// AND zero gcur/embed — one launch, no rocclr fill blits in the graph.
// Blocks 0..191: pack (64 blocks per matrix). Blocks 192..255: zeroing.
// frag index: f = ((ct*4 + ks)*64 + lane)*8 + j
//   c = ct*16 + (lane&15), k = ks*32 + (lane>>4)*8 + j
// =====================================================================
__global__ __launch_bounds__(256) void setup_kernel(
    const float* __restrict__ W0, const float* __restrict__ W1, const float* __restrict__ W2,
    unsigned short* __restrict__ wpk,   // [6][16384]: w0h w0l w1h w1l w2h w2l
    int* __restrict__ gcur, float* __restrict__ embed)
{
    int b = blockIdx.x;
    if (b < 192) {
        int mat = b >> 6;
        const float* W = (mat == 0) ? W0 : (mat == 1) ? W1 : W2;
        unsigned short* Wh = wpk + (size_t)(2 * mat) * 16384;
        unsigned short* Wl = Wh + 16384;
        int f = (b & 63) * 256 + threadIdx.x;
        int j    = f & 7;
        int lane = (f >> 3) & 63;
        int ctks = f >> 9;
        int ct = ctks >> 2, ks = ctks & 3;
        int c = ct * 16 + (lane & 15);
        int k = ks * 32 + (lane >> 4) * 8 + j;
        float v = W[c * 128 + k];
        unsigned short h = f2bf(v);
        float hf = __uint_as_float((unsigned)h << 16);
        Wh[f] = h;
        Wl[f] = f2bf(v - hf);
    } else {
        int i = (b - 192) * 256 + threadIdx.x;   // 0..16383
        embed[i] = 0.f;
        if (i < 512) gcur[i] = 0;
    }
}

// =====================================================================
// MFMA GEMM (C^T tiles, no LDS): mfma(A_op = W-tile, B_op = node rows).
// 16 nodes/wave, 4 waves/block. A_F32: hi/lo-split A (3 mfma); else 2 mfma.
// bias nullable. RELU applies to the bf16 output; raw f32 out is pre-relu.
// =====================================================================
template <bool A_F32, bool RELU>
__global__ __launch_bounds__(256) void gemm_mfma(
    const void* __restrict__ Aptr,
    const unsigned short* __restrict__ Wh, const unsigned short* __restrict__ Wl,
    const float* __restrict__ bias,
    unsigned short* __restrict__ out_bf16,
    float* __restrict__ out_raw_f32, int M)
{
    int wid  = threadIdx.x >> 6;
    int lane = threadIdx.x & 63;
    int n0 = blockIdx.x * 64 + wid * 16;
    if (n0 >= M) return;
    int kb = lane >> 4;
    int row = n0 + (lane & 15);

    f32x4 acc[8];
#pragma unroll
    for (int ct = 0; ct < 8; ++ct) acc[ct] = (f32x4){0.f, 0.f, 0.f, 0.f};

#pragma unroll
    for (int ks = 0; ks < 4; ++ks) {
        bf16x8 ah, al;
        if (A_F32) {
            const float* A = (const float*)Aptr;
            f32x4 a0 = *(const f32x4*)(A + (size_t)row * 128 + ks * 32 + kb * 8);
            f32x4 a1 = *(const f32x4*)(A + (size_t)row * 128 + ks * 32 + kb * 8 + 4);
            float av[8] = {a0[0], a0[1], a0[2], a0[3], a1[0], a1[1], a1[2], a1[3]};
#pragma unroll
            for (int j = 0; j < 8; ++j) {
                unsigned short h = f2bf(av[j]);
                float hf = __uint_as_float((unsigned)h << 16);
                ah[j] = (short)h;
                al[j] = (short)f2bf(av[j] - hf);
            }
        } else {
            ah = *(const bf16x8*)((const unsigned short*)Aptr + (size_t)row * 128 + ks * 32 + kb * 8);
        }
#pragma unroll
        for (int ct = 0; ct < 8; ++ct) {
            size_t wf = ((size_t)(ct * 4 + ks) * 64 + lane) * 8;
            bf16x8 wh = *(const bf16x8*)(Wh + wf);
            bf16x8 wl = *(const bf16x8*)(Wl + wf);
            acc[ct] = __builtin_amdgcn_mfma_f32_16x16x32_bf16(wh, ah, acc[ct], 0, 0, 0);
            if (A_F32)
                acc[ct] = __builtin_amdgcn_mfma_f32_16x16x32_bf16(wh, al, acc[ct], 0, 0, 0);
            acc[ct] = __builtin_amdgcn_mfma_f32_16x16x32_bf16(wl, ah, acc[ct], 0, 0, 0);
        }
    }

#pragma unroll
    for (int ct = 0; ct < 8; ++ct) {
        int c0 = ct * 16 + kb * 4;
        f32x4 r = acc[ct];
        if (bias) {
            f32x4 bv = *(const f32x4*)(bias + c0);
            r += bv;
        }
        if (out_raw_f32) *(f32x4*)(out_raw_f32 + (size_t)row * 128 + c0) = r;
        if (RELU) {
            r[0] = fmaxf(r[0], 0.f); r[1] = fmaxf(r[1], 0.f);
            r[2] = fmaxf(r[2], 0.f); r[3] = fmaxf(r[3], 0.f);
        }
        ushort4 ob;
        ob.x = f2bf(r[0]); ob.y = f2bf(r[1]); ob.z = f2bf(r[2]); ob.w = f2bf(r[3]);
        *(ushort4*)(out_bf16 + (size_t)row * 128 + c0) = ob;
    }
}

// =====================================================================
// Pass A: LDS counting-sort 4096 edges into 391 coarse buckets (dst>>7),
// write each bucket run contiguously to its global region (atomic reserve).
// Edge packed as (src<<7)|(dst&127) — 4B.
// =====================================================================
__global__ __launch_bounds__(256) void bucket_a(
    const int* __restrict__ esrc, const int* __restrict__ edst,
    int* __restrict__ gcur, unsigned* __restrict__ bdata)
{
    __shared__ unsigned sp[BLK_E];      // 16KB
    __shared__ int shist[512];
    __shared__ int sscan[512];
    __shared__ int sgbase[NBKT];
    __shared__ int scur[NBKT];
    __shared__ int wtot[4];

    int t = threadIdx.x;
    int e0 = blockIdx.x * BLK_E;
    shist[t] = 0; shist[t + 256] = 0;
    __syncthreads();

    int vv[NPT]; int bb[NPT];
#pragma unroll
    for (int i = 0; i < NPT; ++i) {
        int e = e0 + t + i * 256;
        if (e < N_EDGES) {
            int s = esrc[e], d = edst[e];
            bb[i] = d >> 7;
            vv[i] = (s << 7) | (d & 127);
            atomicAdd(&shist[bb[i]], 1);
        } else bb[i] = -1;
    }
    __syncthreads();

    // exclusive scan of 512 counts
    {
        int lane = t & 63, w = t >> 6;
        int a0 = shist[2 * t], a1 = shist[2 * t + 1];
        int s = a0 + a1, inc = s;
#pragma unroll
        for (int d = 1; d < 64; d <<= 1) {
            int y = __shfl_up(inc, d, 64);
            if (lane >= d) inc += y;
        }
        if (lane == 63) wtot[w] = inc;
        __syncthreads();
        int woff = 0;
        for (int j = 0; j < w; ++j) woff += wtot[j];
        int excl = woff + inc - s;
        sscan[2 * t] = excl;
        sscan[2 * t + 1] = excl + a0;
    }
    __syncthreads();

    // reserve global space per bucket; init local cursors
    for (int b = t; b < NBKT; b += 256) {
        int c = shist[b];
        sgbase[b] = c ? atomicAdd(&gcur[b], c) : 0;
        scur[b] = sscan[b];
    }
    __syncthreads();

    // scatter into LDS grouped by bucket
#pragma unroll
    for (int i = 0; i < NPT; ++i) {
        if (bb[i] >= 0) {
            int pos = atomicAdd(&scur[bb[i]], 1);
            sp[pos] = (unsigned)vv[i];
        }
    }
    __syncthreads();

    // copy runs out: wave w handles buckets w, w+4, ...
    int lane = t & 63, w = t >> 6;
    for (int b = w; b < NBKT; b += 4) {
        int c = shist[b];
        int lo = sscan[b];
        unsigned gb = (unsigned)b * BCAP + (unsigned)sgbase[b];
        for (int j = lane; j < c; j += 64)
            bdata[gb + j] = sp[lo + j];
    }
}

// =====================================================================
// Exclusive scan of 391 bucket counts -> csr base per bucket; off[N]=E.
// =====================================================================
__global__ __launch_bounds__(256) void scan_buckets(
    const int* __restrict__ gcur, int* __restrict__ csrbase, int* __restrict__ off)
{
    __shared__ int wtot[4];
    int t = threadIdx.x;
    int lane = t & 63, w = t >> 6;
    int a0 = (2 * t < NBKT) ? gcur[2 * t] : 0;
    int a1 = (2 * t + 1 < NBKT) ? gcur[2 * t + 1] : 0;
    int s = a0 + a1, inc = s;
#pragma unroll
    for (int d = 1; d < 64; d <<= 1) {
        int y = __shfl_up(inc, d, 64);
        if (lane >= d) inc += y;
    }
    if (lane == 63) wtot[w] = inc;
    __syncthreads();
    int woff = 0;
    for (int j = 0; j < w; ++j) woff += wtot[j];
    int excl = woff + inc - s;
    if (2 * t < NBKT) csrbase[2 * t] = excl;
    if (2 * t + 1 < NBKT) csrbase[2 * t + 1] = excl + a0;
    if (t == 0) off[N_NODES] = N_EDGES;
}

// =====================================================================
// Pass B: per bucket, LDS counting-sort by dst&127; write off[] and csr
// fully sequentially.
// =====================================================================
__global__ __launch_bounds__(256) void bucket_b(
    const int* __restrict__ gcur, const int* __restrict__ csrbase,
    const unsigned* __restrict__ bdata,
    int* __restrict__ off, int* __restrict__ csr)
{
    __shared__ unsigned sp[BCAP];       // 10KB
    __shared__ unsigned sq[BCAP];       // 10KB
    __shared__ int h[128], sc[128], cur[128];

    int b = blockIdx.x;
    int t = threadIdx.x;
    int cnt = gcur[b];
    if (cnt > BCAP) cnt = BCAP;         // defensive (statistically impossible)
    const unsigned* reg = bdata + (size_t)b * BCAP;

    if (t < 128) h[t] = 0;
    __syncthreads();
    for (int i = t; i < cnt; i += 256) {
        unsigned v = reg[i];
        sp[i] = v;
        atomicAdd(&h[v & 127], 1);
    }
    __syncthreads();
    if (t < 64) {
        int a0 = h[2 * t], a1 = h[2 * t + 1];
        int s = a0 + a1, inc = s;
#pragma unroll
        for (int d = 1; d < 64; d <<= 1) {
            int y = __shfl_up(inc, d, 64);
            if (t >= d) inc += y;
        }
        int excl = inc - s;
        sc[2 * t] = excl;          cur[2 * t] = excl;
        sc[2 * t + 1] = excl + a0; cur[2 * t + 1] = excl + a0;
    }
    __syncthreads();
    int base = csrbase[b];
    if (t < 128) {
        int node = b * 128 + t;
        if (node < N_NODES) off[node] = base + sc[t];
    }
    for (int i = t; i < cnt; i += 256) {
        unsigned v = sp[i];
        int pos = atomicAdd(&cur[v & 127], 1);
        sq[pos] = v >> 7;
    }
    __syncthreads();
    for (int i = t; i < cnt; i += 256)
        csr[base + i] = (int)sq[i];
}

// =====================================================================
// SpMM + level epilogue: cur[n] = relu( sum_{e in row n} Z[csr[e]] + b + im[n] )
// one wave per node; lane handles 2 channels (4B). unroll 8 for MLP.
// =====================================================================
__global__ __launch_bounds__(64) void spmm_ep(
    const int* __restrict__ off, const int* __restrict__ csr,
    const unsigned short* __restrict__ Z,
    const float* __restrict__ bias, const float* __restrict__ im,
    unsigned short* __restrict__ curOut)
{
    int n = blockIdx.x;
    int t = threadIdx.x;
    int lo = off[n], hi = off[n + 1];
    float ax = 0.f, ay = 0.f;
    int e = lo;
    for (; e + 8 <= hi; e += 8) {
        unsigned v[8];
#pragma unroll
        for (int j = 0; j < 8; ++j) {
            int s = csr[e + j];
            v[j] = *(const unsigned*)(Z + (size_t)s * 128 + 2 * t);
        }
#pragma unroll
        for (int j = 0; j < 8; ++j) {
            ax += __uint_as_float(v[j] << 16);
            ay += __uint_as_float(v[j] & 0xffff0000u);
        }
    }
    for (; e + 4 <= hi; e += 4) {
        unsigned v0 = *(const unsigned*)(Z + (size_t)csr[e] * 128 + 2 * t);
        unsigned v1 = *(const unsigned*)(Z + (size_t)csr[e + 1] * 128 + 2 * t);
        unsigned v2 = *(const unsigned*)(Z + (size_t)csr[e + 2] * 128 + 2 * t);
        unsigned v3 = *(const unsigned*)(Z + (size_t)csr[e + 3] * 128 + 2 * t);
        ax += __uint_as_float(v0 << 16) + __uint_as_float(v1 << 16)
            + __uint_as_float(v2 << 16) + __uint_as_float(v3 << 16);
        ay += __uint_as_float(v0 & 0xffff0000u) + __uint_as_float(v1 & 0xffff0000u)
            + __uint_as_float(v2 & 0xffff0000u) + __uint_as_float(v3 & 0xffff0000u);
    }
    for (; e < hi; ++e) {
        unsigned v = *(const unsigned*)(Z + (size_t)csr[e] * 128 + 2 * t);
        ax += __uint_as_float(v << 16);
        ay += __uint_as_float(v & 0xffff0000u);
    }
    float2 iv = *(const float2*)(im + (size_t)n * 128 + 2 * t);
    float2 bv = *(const float2*)(bias + 2 * t);
    float rx = fmaxf(ax + bv.x + iv.x, 0.f);
    float ry = fmaxf(ay + bv.y + iv.y, 0.f);
    unsigned out = (unsigned)f2bf(rx) | ((unsigned)f2bf(ry) << 16);
    *(unsigned*)(curOut + (size_t)n * 128 + 2 * t) = out;
}

// =====================================================================
// Per-graph sum pooling (bf16 input): chunked partial sums + atomicAdd.
// =====================================================================
#define PCHUNK 64
__global__ __launch_bounds__(128) void pool_partial(
    const unsigned short* __restrict__ X, const int* __restrict__ gid,
    float* __restrict__ embed)
{
    int n0 = blockIdx.x * PCHUNK;
    int t = threadIdx.x;
    int end = n0 + PCHUNK; if (end > N_NODES) end = N_NODES;
    float acc = 0.f;
    int g = gid[n0];
    for (int n = n0; n < end; ++n) {
        int gn = gid[n];
        if (gn != g) {
            atomicAdd(&embed[g * 128 + t], acc);
            acc = 0.f; g = gn;
        }
        acc += __uint_as_float((unsigned)X[(size_t)n * 128 + t] << 16);
    }
    atomicAdd(&embed[g * 128 + t], acc);
}

// =====================================================================
// Classifier head (f32).
// =====================================================================
__global__ __launch_bounds__(256) void head_kernel(
    const float* __restrict__ embed,
    const float* __restrict__ w_h1, const float* __restrict__ b_h1,
    const float* __restrict__ w_h2, const float* __restrict__ b_h2,
    const int* __restrict__ labels,
    float* __restrict__ logits, float* __restrict__ nll, float* __restrict__ corr)
{
    int g = blockIdx.x;
    int t = threadIdx.x;
    __shared__ float se[128];
    __shared__ float sh[256];
    __shared__ float sl[NC];
    __shared__ float s_lse;
    if (t < 128) se[t] = fmaxf(embed[g * 128 + t], 0.f);
    __syncthreads();

    float h = b_h1[t];
    const float* wr = w_h1 + (size_t)t * 128;
    for (int k = 0; k < 128; ++k) h += se[k] * wr[k];
    sh[t] = fmaxf(h, 0.f);
    __syncthreads();

    if (t < NC) {
        float z = b_h2[t];
        const float* w2 = w_h2 + (size_t)t * 256;
        for (int k = 0; k < 256; ++k) z += sh[k] * w2[k];
        sl[t] = z;
    }
    __syncthreads();

    if (t == 0) {
        float m = sl[0];
        int am = 0;
        for (int c = 1; c < NC; ++c) if (sl[c] > m) { m = sl[c]; am = c; }
        float s = 0.f;
        for (int c = 0; c < NC; ++c) s += expf(sl[c] - m);
        float lse = m + logf(s);
        s_lse = lse;
        int lab = labels[g];
        nll[g] = lse - sl[lab];
        corr[g] = (am == lab) ? 1.f : 0.f;
    }
    __syncthreads();
    if (t < NC) logits[g * NC + t] = sl[t] - s_lse;
}

__global__ __launch_bounds__(64) void finalize_kernel(
    const float* __restrict__ nll, const float* __restrict__ corr,
    float* __restrict__ out)
{
    int t = threadIdx.x;
    float a = nll[t] + nll[t + 64];
    float b = corr[t] + corr[t + 64];
    for (int d = 32; d; d >>= 1) {
        a += __shfl_down(a, d);
        b += __shfl_down(b, d);
    }
    if (t == 0) {
        out[N_GRAPH * NC + 0] = a / (float)N_GRAPH;
        out[N_GRAPH * NC + 1] = b / (float)N_GRAPH;
    }
}

// =====================================================================
extern "C" void kernel_launch(void* const* d_in, const int* in_sizes, int n_in,
                              void* d_out, int out_size, void* d_ws, size_t ws_size,
                              hipStream_t stream)
{
    const float* node_feat = (const float*)d_in[0];
    const int*   edge_src  = (const int*)d_in[1];
    const int*   edge_dst  = (const int*)d_in[2];
    const int*   graph_id  = (const int*)d_in[3];
    const int*   labels    = (const int*)d_in[4];
    const float* w_n2l     = (const float*)d_in[5];
    const float* b_n2l     = (const float*)d_in[6];
    const float* w_conv    = (const float*)d_in[7];
    const float* b_conv    = (const float*)d_in[8];
    const float* w_out     = (const float*)d_in[9];
    const float* b_out     = (const float*)d_in[10];
    const float* w_h1      = (const float*)d_in[11];
    const float* b_h1      = (const float*)d_in[12];
    const float* w_h2      = (const float*)d_in[13];
    const float* b_h2      = (const float*)d_in[14];

    char* ws = (char*)d_ws;
    float*          im      = (float*)(ws + OFS_IM);
    unsigned short* curb    = (unsigned short*)(ws + OFS_CURB);
    unsigned short* zb      = (unsigned short*)(ws + OFS_ZB);
    int*            off     = (int*)(ws + OFS_OFF);
    int*            gcur    = (int*)(ws + OFS_GCUR);
    int*            csrbase = (int*)(ws + OFS_CSB);
    int*            csr     = (int*)(ws + OFS_CSR);
    unsigned*       bdata   = (unsigned*)(ws + OFS_BKT);
    float*          embed   = (float*)(ws + OFS_EMB);
    float*          nll     = (float*)(ws + OFS_NLL);
    float*          corr    = (float*)(ws + OFS_COR);
    unsigned short* wpk     = (unsigned short*)(ws + OFS_WPK);
    unsigned short* w0h = wpk;              unsigned short* w0l = wpk + 16384;
    unsigned short* w1h = wpk + 2 * 16384;  unsigned short* w1l = wpk + 3 * 16384;
    unsigned short* w2h = wpk + 4 * 16384;  unsigned short* w2l = wpk + 5 * 16384;
    float*          outp    = (float*)d_out;

    const int gemm_blocks = (N_NODES + 63) / 64;
    const int pool_blocks = (N_NODES + PCHUNK - 1) / PCHUNK;
    const int bktA_blocks = (N_EDGES + BLK_E - 1) / BLK_E;

    // 0. pack weights (MFMA fragment order, hi/lo) + zero gcur/embed
    setup_kernel<<<256, 256, 0, stream>>>(w_n2l, w_conv, w_out, wpk, gcur, embed);

    // 1. input_message: im = node_feat @ w_n2l.T + b (raw f32); curb = bf16(relu)
    gemm_mfma<true, true><<<gemm_blocks, 256, 0, stream>>>(
        node_feat, w0h, w0l, b_n2l, curb, im, N_NODES);

    // 2. build CSR by dst (two-pass bucket sort, cache-friendly writes)
    bucket_a<<<bktA_blocks, 256, 0, stream>>>(edge_src, edge_dst, gcur, bdata);
    scan_buckets<<<1, 256, 0, stream>>>(gcur, csrbase, off);
    bucket_b<<<NBKT, 256, 0, stream>>>(gcur, csrbase, bdata, off, csr);

    // 3. three mean-field levels via linearity: z = cur @ Wc.T (GEMM first),
    //    then cur = relu(spmm(z) + b_conv + im) with fused epilogue.
    for (int lv = 0; lv < 3; ++lv) {
        gemm_mfma<false, false><<<gemm_blocks, 256, 0, stream>>>(
            curb, w1h, w1l, nullptr, zb, nullptr, N_NODES);
        spmm_ep<<<N_NODES, 64, 0, stream>>>(off, csr, zb, b_conv, im, curb);
    }

    // 4. out = relu(curb @ w_out.T + b_out) -> bf16 into zb
    gemm_mfma<false, true><<<gemm_blocks, 256, 0, stream>>>(
        curb, w2h, w2l, b_out, zb, nullptr, N_NODES);

    // 5. per-graph pooling (sum, relu deferred to head)
    pool_partial<<<pool_blocks, 128, 0, stream>>>(zb, graph_id, embed);

    // 6. classifier head
    head_kernel<<<N_GRAPH, 256, 0, stream>>>(embed, w_h1, b_h1, w_h2, b_h2, labels,
                                             outp, nll, corr);

    // 7. loss & acc
    finalize_kernel<<<1, 64, 0, stream>>>(nll, corr, outp);
}